// Round 5
// baseline (2154.052 us; speedup 1.0000x reference)
//
#include <hip/hip_runtime.h>
#include <hip/hip_bf16.h>

typedef __attribute__((ext_vector_type(8))) short bf16x8;   // MFMA A/B frag (16B)
typedef __attribute__((ext_vector_type(4))) float f32x4;    // MFMA C/D frag
using bf16 = __hip_bfloat16;
typedef unsigned long long u64;

constexpr int BB = 64, TT = 256, DIN = 512, HH = 1024, DOUT = 512;
constexpr int P0 = 1544;       // LDS pitch for W0 rows (1536 + 8)
constexpr int P1 = 2056;       // LDS pitch for W1 rows (2048 + 8)
constexpr int HWORDS = 8192;   // one h half-array: 128 koct x 64 rows (u64)
constexpr int PARSTRIDE = 2 * HWORDS;  // u64 per h slot (lo+hi) = 128 KB
constexpr int NW = 8;          // waves per block (2 per SIMD -> TLP)

#define MFMA16(a, b, c) __builtin_amdgcn_mfma_f32_16x16x32_bf16((a), (b), (c), 0, 0, 0)
#define ALOAD(p)  __hip_atomic_load((p),  __ATOMIC_RELAXED, __HIP_MEMORY_SCOPE_AGENT)
#define ASTORE(p, v) __hip_atomic_store((p), (v), __ATOMIC_RELAXED, __HIP_MEMORY_SCOPE_AGENT)

union frag_u { u64 q[2]; bf16x8 f; };

__device__ __forceinline__ short f2b(float f) {
  __hip_bfloat16 h = __float2bfloat16(f);           // RNE
  return *reinterpret_cast<short*>(&h);
}
__device__ __forceinline__ u64 pack4(float4 v) {
  return (u64)(unsigned short)f2b(v.x) | ((u64)(unsigned short)f2b(v.y) << 16) |
         ((u64)(unsigned short)f2b(v.z) << 32) | ((u64)(unsigned short)f2b(v.w) << 48);
}

// gate math: z -> (h bf16 bits), updates c register
__device__ __forceinline__ unsigned short gates(const float zv[4], const float br[4],
                                                float scale, float& cr, bool first) {
  float zf = (zv[0] + br[0]) * scale;
  float zi = (zv[1] + br[1]) * scale;
  float zo = (zv[2] + br[2]) * scale;
  float zg = (zv[3] + br[3]) * scale;
  float f = 1.0f / (1.0f + __expf(-zf));
  float i = 1.0f / (1.0f + __expf(-zi));
  float o = 1.0f / (1.0f + __expf(-zo));
  float g = tanhf(zg);
  float cn = f * (first ? 0.0f : cr) + i * g;
  cr = cn;
  __hip_bfloat16 hv = __float2bfloat16(o * tanhf(cn));
  return *reinterpret_cast<unsigned short*>(&hv);
}

// ---------------- persistent kernel: 256 blocks x 512 threads (8 waves), 1 block/CU --------
// Round-0 proven structure + ADAPTIVE-DEPTH fresh h slots (round-5):
// h0(t)/h1(t) go to slot (t & dmask) in a depth-D ring (D = largest of {256,128,64,32}
// that fits ws; round-4's fixed D=256 never fit -> silent ring fallback). Fresh slots make
// plain cached reads coherent BY CONSTRUCTION for D steps (write-once addresses: a reader's
// L1/L2 can only miss-to-IC-fresh); 32 blocks/XCD then share one L2 refill per slot instead
// of 32 independent IC fetches (round-0's 64MB/step bottleneck). Slot REUSE after D steps
// reintroduces staleness, fixed by a RARE agent-acquire fence (buffer_inv) every invp=D-8
// steps: block skew <=2, data read at step u is rewritten at u+D, and fences spaced
// invp<=D-5 guarantee an invalidate strictly inside (u+2, u+D-1) for every u (incl. the
// final FC reads). 2-10 fences total vs round-3's 512 (which cost +25us/step).
// Ring+ALOAD fallback (exact round-0 semantics) only if even D=32-no-xb doesn't fit.
__global__ void __launch_bounds__(512, 1)
lstm_persist(const float* __restrict__ x,  const float* __restrict__ W0,
             const float* __restrict__ b0, const float* __restrict__ W1,
             const float* __restrict__ b1, const float* __restrict__ Wfc,
             const float* __restrict__ bfc,
             u64* __restrict__ xbu, int use_xb, int use_fresh, int dmask, int invp,
             u64* __restrict__ h0s, u64* __restrict__ h1s,
             unsigned* __restrict__ flagsA, unsigned* __restrict__ flagsB,
             float* __restrict__ out) {
  __shared__ unsigned short lw0[16 * P0];            // 49.4 KB  W0^T cols, bf16
  __shared__ unsigned short lw1[16 * P1];            // 65.8 KB  W1^T cols, bf16
  __shared__ float zbuf[NW][4][16][17];              // 34.8 KB  cross-wave z partials
  __shared__ unsigned short hs[64][4];               // 0.5 KB   h-tile staging

  const int tid  = threadIdx.x;
  const int wg   = blockIdx.x;
  const int lane = tid & 63;
  const int wv   = tid >> 6;          // wave id 0..7 = K-eighth
  const int n    = lane & 15;
  const int oct  = lane >> 4;
  const int mg   = tid & 63;          // epilogue row (tid<256 only)
  const int hq   = tid >> 6;          // epilogue hcol offset (tid<256 only)
  const float S0 = 1.0f / sqrtf((float)(DIN + HH));
  const float S1 = 1.0f / sqrtf((float)(HH + HH));

  float c0r = 0.0f, c1r = 0.0f;
  float b0r[4] = {0, 0, 0, 0}, b1r[4] = {0, 0, 0, 0};
  if (tid < 256) {
    const int hcol = wg * 4 + hq;
#pragma unroll
    for (int g = 0; g < 4; ++g) { b0r[g] = b0[g * HH + hcol]; b1r[g] = b1[g * HH + hcol]; }
  }

  // ---- stage this block's 16 columns of W0/W1 into LDS (fp32 -> bf16, transposed) ----
  {
    const int g = tid >> 7, kw = tid & 127;
    const int col0 = g * HH + wg * 4;
    for (int k = kw; k < DIN + HH; k += 128) {
      float4 u = *(const float4*)(W0 + (size_t)k * 4096 + col0);
      lw0[(g * 4 + 0) * P0 + k] = (unsigned short)f2b(u.x);
      lw0[(g * 4 + 1) * P0 + k] = (unsigned short)f2b(u.y);
      lw0[(g * 4 + 2) * P0 + k] = (unsigned short)f2b(u.z);
      lw0[(g * 4 + 3) * P0 + k] = (unsigned short)f2b(u.w);
    }
    for (int k = kw; k < 2 * HH; k += 128) {
      float4 u = *(const float4*)(W1 + (size_t)k * 4096 + col0);
      lw1[(g * 4 + 0) * P1 + k] = (unsigned short)f2b(u.x);
      lw1[(g * 4 + 1) * P1 + k] = (unsigned short)f2b(u.y);
      lw1[(g * 4 + 2) * P1 + k] = (unsigned short)f2b(u.z);
      lw1[(g * 4 + 3) * P1 + k] = (unsigned short)f2b(u.w);
    }
  }

  // ---- epoch 0: convert x -> bf16 split layout xb[t][koct 64][row 64] (16B units) ----
  if (use_xb) {
    const int t = wg;                 // block wg converts timestep wg
    for (int u = tid; u < 64 * 64; u += 512) {
      const int row = u & 63, ko = u >> 6;
      const float* p = x + ((size_t)row * TT + t) * DIN + ko * 8;
      float4 A = *(const float4*)p, B = *(const float4*)(p + 4);
      u64* d = xbu + ((size_t)(t * 64 + ko) * 64 + row) * 2;
      ASTORE(d, pack4(A));
      ASTORE(d + 1, pack4(B));
    }
  }
  __syncthreads();                    // drains conv stores (vmcnt 0 before barrier) + LDS staging

  f32x4 z0a[4], z1a[4];
  float zv[4] = {0, 0, 0, 0};

  auto flag_release = [&](unsigned* f, unsigned val) {
    if (tid < 64) __builtin_amdgcn_s_waitcnt(0);     // wave0: drain its sc1 stores
    if (tid == 0) ASTORE(f + wg, val);
  };
  auto bar_wait = [&](unsigned* f, unsigned target) {
    if (tid < 64) {                                  // wave 0 polls 4 flags/thread
      const u64* p = (const u64*)(f + tid * 4);
      for (;;) {
        u64 a = ALOAD(p), b = ALOAD(p + 1);
        if ((unsigned)a >= target && (unsigned)(a >> 32) >= target &&
            (unsigned)b >= target && (unsigned)(b >> 32) >= target) break;
        __builtin_amdgcn_s_sleep(1);
      }
    }
    __syncthreads();
    __builtin_amdgcn_fence(__ATOMIC_ACQUIRE, "workgroup");   // ordering only (no invalidate)
  };
  // h slot for timestep t: depth-D ring (fresh mode: plain-load coherent for D steps)
  auto hslot = [&](u64* arr, int t) -> u64* {
    return arr + (size_t)(t & dmask) * PARSTRIDE;
  };

  flag_release(flagsA, 1u);           // x conversion published
  bar_wait(flagsA, 1u);

  // ---- x-part of layer0(t): 8 cached 16B loads + 8 MFMA per wave ----
  auto xpart = [&](int t) {
    if (use_xb) {
      const bf16* xb = (const bf16*)xbu;
#pragma unroll
      for (int s = 0; s < 2; ++s) {
        const int ko = wv * 8 + s * 4 + oct;
        bf16x8 bw = *(const bf16x8*)&lw0[n * P0 + ko * 8];
#pragma unroll
        for (int rt = 0; rt < 4; ++rt) {
          bf16x8 a = *(const bf16x8*)(xb + ((size_t)(t * 64 + ko) * 64 + rt * 16 + n) * 8);
          z0a[rt] = MFMA16(a, bw, z0a[rt]);
        }
      }
    } else {                          // fallback: fp32 x + on-the-fly cvt (x is read-only: L2-cacheable)
#pragma unroll
      for (int s = 0; s < 2; ++s) {
        const int kp = wv * 64 + s * 32 + oct * 8;
        bf16x8 bw = *(const bf16x8*)&lw0[n * P0 + kp];
#pragma unroll
        for (int rt = 0; rt < 4; ++rt) {
          const float* p = x + ((size_t)(rt * 16 + n) * TT + t) * DIN + kp;
          float4 A = *(const float4*)p, B = *(const float4*)(p + 4);
          bf16x8 a;
          a[0] = f2b(A.x); a[1] = f2b(A.y); a[2] = f2b(A.z); a[3] = f2b(A.w);
          a[4] = f2b(B.x); a[5] = f2b(B.y); a[6] = f2b(B.z); a[7] = f2b(B.w);
          z0a[rt] = MFMA16(a, bw, z0a[rt]);
        }
      }
    }
  };

  // h frag loads: plain cached (fresh slots, L2-shared across XCD) or ALOAD (ring).
  auto hload = [&](const u64* hb, u64 lo[16], u64 hi[16]) {
    if (use_fresh) {
#pragma unroll
      for (int i = 0; i < 16; ++i) {
        const int s = i >> 2, rt = i & 3;
        const int idx = (wv * 16 + s * 4 + oct) * 64 + rt * 16 + n;
        lo[i] = hb[idx];
        hi[i] = hb[HWORDS + idx];
      }
    } else {
#pragma unroll
      for (int i = 0; i < 16; ++i) {
        const int s = i >> 2, rt = i & 3;
        const int idx = (wv * 16 + s * 4 + oct) * 64 + rt * 16 + n;
        lo[i] = ALOAD(hb + idx);
        hi[i] = ALOAD(hb + HWORDS + idx);
      }
    }
  };

  // h0 dual-consume GEMM: z0 += h0*W0[512+k], z1 += h0*W1[k]  (16 frags/wave)
  auto h0gemm = [&](const u64* h0b) {
    u64 lo[16], hi[16];
    hload(h0b, lo, hi);
#pragma unroll
    for (int s = 0; s < 4; ++s) {
      const int kp = wv * 128 + s * 32 + oct * 8;
      bf16x8 bw0 = *(const bf16x8*)&lw0[n * P0 + 512 + kp];
      bf16x8 bw1 = *(const bf16x8*)&lw1[n * P1 + kp];
#pragma unroll
      for (int rt = 0; rt < 4; ++rt) {
        frag_u u; u.q[0] = lo[s * 4 + rt]; u.q[1] = hi[s * 4 + rt];
        z0a[rt] = MFMA16(u.f, bw0, z0a[rt]);
        z1a[rt] = MFMA16(u.f, bw1, z1a[rt]);
      }
    }
  };
  // z1 += h * W1[koff + k]
  auto h1gemm = [&](const u64* hb, int koff) {
    u64 lo[16], hi[16];
    hload(hb, lo, hi);
#pragma unroll
    for (int s = 0; s < 4; ++s) {
      const int kp = wv * 128 + s * 32 + oct * 8;
      bf16x8 bw = *(const bf16x8*)&lw1[n * P1 + koff + kp];
#pragma unroll
      for (int rt = 0; rt < 4; ++rt) {
        frag_u u; u.q[0] = lo[s * 4 + rt]; u.q[1] = hi[s * 4 + rt];
        z1a[rt] = MFMA16(u.f, bw, z1a[rt]);
      }
    }
  };

  auto publish = [&](u64* dst) {                     // dst = slot base
    if (tid < 64) {
      u64 val = *(const u64*)&hs[tid][0];
      ASTORE(dst + (size_t)(wg & 1) * HWORDS + (wg >> 1) * 64 + tid, val);
    }
  };
  auto zreduce = [&](f32x4 za[4]) {
#pragma unroll
    for (int rt = 0; rt < 4; ++rt)
#pragma unroll
      for (int r = 0; r < 4; ++r) zbuf[wv][rt][oct * 4 + r][n] = za[rt][r];
    __syncthreads();
    if (tid < 256) {
#pragma unroll
      for (int g = 0; g < 4; ++g) {
        float s = 0.f;
#pragma unroll
        for (int w = 0; w < NW; ++w) s += zbuf[w][mg >> 4][mg & 15][g * 4 + hq];
        zv[g] = s;
      }
    }
  };

  // =================== window 0: layer0(0), x-part only ===================
#pragma unroll
  for (int rt = 0; rt < 4; ++rt) z0a[rt] = (f32x4){0.f, 0.f, 0.f, 0.f};
  xpart(0);
  zreduce(z0a);
  if (tid < 256) hs[mg][hq] = gates(zv, b0r, S0, c0r, true);
  __syncthreads();
  publish(hslot(h0s, 0));             // h0(0)
  flag_release(flagsA, 2u);
  flag_release(flagsB, 1u);           // vacuous
#pragma unroll
  for (int rt = 0; rt < 4; ++rt) z0a[rt] = (f32x4){0.f, 0.f, 0.f, 0.f};
  xpart(1);

  // =================== windows 1..255 ===================
  int nextinv = (use_fresh && invp) ? invp : 0x7fffffff;
  for (int t = 1; t < TT; ++t) {
    bar_wait(flagsA, (unsigned)t + 1u);             // h0(t-1) visible
    if (t == nextinv) {                             // rare slot-recycle invalidate
      __builtin_amdgcn_fence(__ATOMIC_ACQUIRE, "agent");   // buffer_inv: drop cached h
      nextinv += invp;
    }
#pragma unroll
    for (int rt = 0; rt < 4; ++rt) z1a[rt] = (f32x4){0.f, 0.f, 0.f, 0.f};
    h0gemm(hslot(h0s, t - 1));

    zreduce(z0a);                                   // z0 complete
    if (tid < 256) hs[mg][hq] = gates(zv, b0r, S0, c0r, false);
    __syncthreads();
    publish(hslot(h0s, t));                         // h0(t)
    flag_release(flagsA, (unsigned)t + 2u);         // release h0 chain EARLY

    if (t < TT - 1) {                               // overlap x(t+1)
#pragma unroll
      for (int rt = 0; rt < 4; ++rt) z0a[rt] = (f32x4){0.f, 0.f, 0.f, 0.f};
      xpart(t + 1);
    }

    if (t >= 2) {
      bar_wait(flagsB, (unsigned)t);                // h1(t-2) visible
      h1gemm(hslot(h1s, t - 2), 1024);
    }
    zreduce(z1a);
    if (tid < 256) hs[mg][hq] = gates(zv, b1r, S1, c1r, t == 1);
    __syncthreads();
    publish(hslot(h1s, t - 1));                     // h1(t-1)
    flag_release(flagsB, (unsigned)t + 1u);
  }

  // =================== final window: layer1(255) ===================
  {
    bar_wait(flagsA, 257u);                         // h0(255)
#pragma unroll
    for (int rt = 0; rt < 4; ++rt) z1a[rt] = (f32x4){0.f, 0.f, 0.f, 0.f};
    h1gemm(hslot(h0s, 255), 0);                     // z1 += h0(255) * W1lo
    bar_wait(flagsB, 256u);                         // h1(254) visible
    h1gemm(hslot(h1s, 254), 1024);                  // z1 += h1(254) * W1hi
    zreduce(z1a);
    if (tid < 256) hs[mg][hq] = gates(zv, b1r, S1, c1r, false);
    __syncthreads();
    publish(hslot(h1s, 255));                       // h1(255)
    flag_release(flagsB, 257u);
  }

  // ============ final FC: out = h1(255) @ Wfc + bfc (blocks 0..31) ============
  if (wg < DOUT / 16) {
    bar_wait(flagsB, 257u);
    {  // stage Wfc cols [wg*16, wg*16+16) into lw0 region (fp32 -> bf16)
      const int q = tid >> 7, kw = tid & 127;
      for (int k = kw; k < HH; k += 128) {
        float4 u = *(const float4*)(Wfc + (size_t)k * DOUT + wg * 16 + q * 4);
        lw0[(q * 4 + 0) * P0 + k] = (unsigned short)f2b(u.x);
        lw0[(q * 4 + 1) * P0 + k] = (unsigned short)f2b(u.y);
        lw0[(q * 4 + 2) * P0 + k] = (unsigned short)f2b(u.z);
        lw0[(q * 4 + 3) * P0 + k] = (unsigned short)f2b(u.w);
      }
    }
    __syncthreads();
    if (tid < 256) {
      const int v4 = tid >> 6;                      // 0..3 (waves 0-3 do the FC)
      const u64* hb = hslot(h1s, 255);              // h1(255)
      f32x4 acc0 = {0.f, 0.f, 0.f, 0.f}, acc1 = {0.f, 0.f, 0.f, 0.f};
#pragma unroll
      for (int it = 0; it < 16; ++it) {
        const int idxA = (it * 8 + oct) * 64 + v4 * 16 + n;
        const int idxB = (it * 8 + 4 + oct) * 64 + v4 * 16 + n;
        frag_u uA, uB;
        if (use_fresh) {
          uA.q[0] = hb[idxA]; uA.q[1] = hb[HWORDS + idxA];
          uB.q[0] = hb[idxB]; uB.q[1] = hb[HWORDS + idxB];
        } else {
          uA.q[0] = ALOAD(hb + idxA); uA.q[1] = ALOAD(hb + HWORDS + idxA);
          uB.q[0] = ALOAD(hb + idxB); uB.q[1] = ALOAD(hb + HWORDS + idxB);
        }
        bf16x8 bwA = *(const bf16x8*)&lw0[n * P0 + it * 64 + oct * 8];
        bf16x8 bwB = *(const bf16x8*)&lw0[n * P0 + it * 64 + 32 + oct * 8];
        acc0 = MFMA16(uA.f, bwA, acc0);
        acc1 = MFMA16(uB.f, bwB, acc1);
      }
      float bb = bfc[wg * 16 + n];
#pragma unroll
      for (int r = 0; r < 4; ++r) {
        int row = v4 * 16 + oct * 4 + r;
        out[(size_t)row * DOUT + wg * 16 + n] = acc0[r] + acc1[r] + bb;
      }
    }
  }
}

extern "C" void kernel_launch(void* const* d_in, const int* in_sizes, int n_in,
                              void* d_out, int out_size, void* d_ws, size_t ws_size,
                              hipStream_t stream) {
  const float* x   = (const float*)d_in[0];
  const float* W0  = (const float*)d_in[1];
  const float* b0  = (const float*)d_in[2];
  const float* W1  = (const float*)d_in[3];
  const float* b1  = (const float*)d_in[4];
  const float* Wfc = (const float*)d_in[5];
  const float* bfc = (const float*)d_in[6];

  char* ws = (char*)d_ws;
  unsigned* flagsA = (unsigned*)ws;                   // 256 u32
  unsigned* flagsB = (unsigned*)(ws + 1024);          // 256 u32

  const size_t slotB = (size_t)PARSTRIDE * 8;         // 128 KiB per h slot
  const size_t xbB   = (size_t)TT * 64 * 64 * 16;     // 16 MiB
  const size_t base  = 4096;

  // Tier selection: largest fresh depth that fits; drop xb before dropping freshness.
  // invp = D-8 (window proof needs invp <= D-5 with block skew <=2).
  int D, invp, use_fresh, use_xb;
  if      (ws_size >= base + 2 * 256 * slotB + xbB) { D = 256; invp = 0;   use_fresh = 1; use_xb = 1; }
  else if (ws_size >= base + 2 * 128 * slotB + xbB) { D = 128; invp = 120; use_fresh = 1; use_xb = 1; }
  else if (ws_size >= base + 2 * 64  * slotB + xbB) { D = 64;  invp = 56;  use_fresh = 1; use_xb = 1; }
  else if (ws_size >= base + 2 * 32  * slotB + xbB) { D = 32;  invp = 24;  use_fresh = 1; use_xb = 1; }
  else if (ws_size >= base + 2 * 64  * slotB)       { D = 64;  invp = 56;  use_fresh = 1; use_xb = 0; }
  else if (ws_size >= base + 2 * 32  * slotB)       { D = 32;  invp = 24;  use_fresh = 1; use_xb = 0; }
  else { D = 2; invp = 0; use_fresh = 0;              // round-0 ring + ALOAD semantics
         use_xb = (ws_size >= base + 2 * 2 * slotB + xbB) ? 1 : 0; }

  u64* h0s = (u64*)(ws + base);                       // D slots x 128 KiB
  u64* h1s = h0s + (size_t)D * PARSTRIDE;             // D slots x 128 KiB
  u64* xbu = h1s + (size_t)D * PARSTRIDE;             // 16 MiB (when use_xb)

  hipMemsetAsync(ws, 0, 4096, stream);                // zero both flag arrays

  lstm_persist<<<dim3(256), dim3(512), 0, stream>>>(
      x, W0, b0, W1, b1, Wfc, bfc, xbu, use_xb, use_fresh, D - 1, invp,
      h0s, h1s, flagsA, flagsB, (float*)d_out);
}